// Round 1
// baseline (1996.939 us; speedup 1.0000x reference)
//
#include <hip/hip_runtime.h>
#include <hip/hip_bf16.h>

#define NF 100000
#define NC 10000
#define EF 800000
#define DF 768
#define DC 128
#define H  128
#define B  256

// ---------------------------------------------------------------- zero
__global__ void zero_kernel(float* p, int n) {
    int i = blockIdx.x * 256 + threadIdx.x;
    if (i < n) p[i] = 0.0f;
}

// ---------------------------------------------------- edge gate + degrees
__global__ void gate_deg_kernel(const float* __restrict__ ea,
                                const int* __restrict__ src,
                                const int* __restrict__ dst,
                                const float* __restrict__ Wm,
                                const float* __restrict__ bm,
                                float* __restrict__ w_out,
                                float* __restrict__ deg_s,
                                float* __restrict__ deg_d,
                                int* __restrict__ cnt_dst,
                                int n_edges) {
    int e = blockIdx.x * 256 + threadIdx.x;
    if (e >= n_edges) return;
    float2 a = ((const float2*)ea)[e];
    float z = a.x * Wm[0] + a.y * Wm[1] + bm[0];
    float w = 1.0f / (1.0f + expf(-z));
    w_out[e] = w;
    atomicAdd(&deg_s[src[e]], w);
    atomicAdd(&deg_d[dst[e]], w);
    atomicAdd(&cnt_dst[dst[e]], 1);
}

// ------------------------------------------------- exclusive scan (2 arrays)
// block 0 scans cnt0[n0] -> off0/cur0, block 1 scans cnt1[n1] -> off1/cur1
__global__ __launch_bounds__(1024) void scan_kernel(const int* __restrict__ cnt0, int* off0, int* cur0, int n0,
                            const int* __restrict__ cnt1, int* off1, int* cur1, int n1) {
    const int* cnt; int* off; int* cur; int n;
    if (blockIdx.x == 0) { cnt = cnt0; off = off0; cur = cur0; n = n0; }
    else                 { cnt = cnt1; off = off1; cur = cur1; n = n1; }
    const int T = 1024;
    int t = threadIdx.x;
    int chunk = (n + T - 1) / T;
    int lo = t * chunk;
    int hi = lo + chunk; if (hi > n) hi = n;
    int lsum = 0;
    for (int i = lo; i < hi; i++) lsum += cnt[i];
    __shared__ int sdata[1024];
    sdata[t] = lsum;
    __syncthreads();
    for (int offst = 1; offst < T; offst <<= 1) {
        int v = (t >= offst) ? sdata[t - offst] : 0;
        __syncthreads();
        sdata[t] += v;
        __syncthreads();
    }
    int excl = sdata[t] - lsum;
    int total = sdata[T - 1];
    int run = excl;
    for (int i = lo; i < hi; i++) {
        off[i] = run; cur[i] = run;
        run += cnt[i];
    }
    if (t == 0) off[n] = total;
}

// ------------------------------------------------------------- CSR fill
__global__ void fill_kernel(const int* __restrict__ dst,
                            int* __restrict__ cur,
                            int* __restrict__ elist, int n_edges) {
    int e = blockIdx.x * 256 + threadIdx.x;
    if (e >= n_edges) return;
    int p = atomicAdd(&cur[dst[e]], 1);
    elist[p] = e;
}

// ---------------------------------------------------------------- GEMM
// C[M x 128] = A[M x K] @ Bm[K x 128], fp32, row-major, K % 32 == 0
#define BM 128
#define BN 128
#define BK 32
__global__ __launch_bounds__(256) void gemm_kernel(const float* __restrict__ A,
                                                   const float* __restrict__ Bm,
                                                   float* __restrict__ C,
                                                   int M, int K) {
    __shared__ float As[BM][BK + 1];
    __shared__ float Bs[BK][BN];
    int t = threadIdx.x;
    int tx = t & 15;   // col group: cols tx*8 .. tx*8+7
    int ty = t >> 4;   // row group: rows ty*8 .. ty*8+7
    int row0 = blockIdx.x * BM;
    float acc[8][8] = {};

    for (int k0 = 0; k0 < K; k0 += BK) {
        // stage A: 128 rows x 32 cols (1024 float4)
        #pragma unroll
        for (int i = 0; i < 4; i++) {
            int idx = t + i * 256;
            int r  = idx >> 3;
            int c4 = idx & 7;
            float4 v = make_float4(0.f, 0.f, 0.f, 0.f);
            int gr = row0 + r;
            if (gr < M) v = *(const float4*)(&A[(long long)gr * K + k0 + c4 * 4]);
            As[r][c4 * 4 + 0] = v.x;
            As[r][c4 * 4 + 1] = v.y;
            As[r][c4 * 4 + 2] = v.z;
            As[r][c4 * 4 + 3] = v.w;
        }
        // stage B: 32 rows x 128 cols (1024 float4)
        #pragma unroll
        for (int i = 0; i < 4; i++) {
            int idx = t + i * 256;
            int kr = idx >> 5;
            int c4 = idx & 31;
            float4 v = *(const float4*)(&Bm[(long long)(k0 + kr) * BN + c4 * 4]);
            *(float4*)(&Bs[kr][c4 * 4]) = v;
        }
        __syncthreads();
        #pragma unroll
        for (int kk = 0; kk < BK; kk++) {
            float a[8], b[8];
            #pragma unroll
            for (int r = 0; r < 8; r++) a[r] = As[ty * 8 + r][kk];
            float4 b0 = *(const float4*)(&Bs[kk][tx * 8]);
            float4 b1 = *(const float4*)(&Bs[kk][tx * 8 + 4]);
            b[0] = b0.x; b[1] = b0.y; b[2] = b0.z; b[3] = b0.w;
            b[4] = b1.x; b[5] = b1.y; b[6] = b1.z; b[7] = b1.w;
            #pragma unroll
            for (int r = 0; r < 8; r++)
                #pragma unroll
                for (int c = 0; c < 8; c++)
                    acc[r][c] += a[r] * b[c];
        }
        __syncthreads();
    }
    #pragma unroll
    for (int r = 0; r < 8; r++) {
        int gr = row0 + ty * 8 + r;
        if (gr < M) {
            float4 o0 = make_float4(acc[r][0], acc[r][1], acc[r][2], acc[r][3]);
            float4 o1 = make_float4(acc[r][4], acc[r][5], acc[r][6], acc[r][7]);
            *(float4*)(&C[(long long)gr * BN + tx * 8 + 0]) = o0;
            *(float4*)(&C[(long long)gr * BN + tx * 8 + 4]) = o1;
        }
    }
}

// ------------------------------------------- fc aggregation -> c1 (relu+bias)
// one block (128 threads) per company dst node
__global__ __launch_bounds__(128) void agg_fc_kernel(const int* __restrict__ off,
                                                     const int* __restrict__ elist,
                                                     const int* __restrict__ srcs,
                                                     const float* __restrict__ w,
                                                     const float* __restrict__ deg_s,
                                                     const float* __restrict__ deg_d,
                                                     const float* __restrict__ h1,
                                                     const float* __restrict__ bias,
                                                     float* __restrict__ c1out) {
    int d = blockIdx.x;
    int t = threadIdx.x;
    int start = off[d], end = off[d + 1];
    __shared__ int   s_src[128];
    __shared__ float s_nrm[128];
    float dd  = deg_d[d];
    float rdd = dd > 0.f ? rsqrtf(dd) : 0.f;
    float acc = 0.f;
    for (int base = start; base < end; base += 128) {
        int j = base + t;
        if (j < end) {
            int e = elist[j];
            int s = srcs[e];
            float ds = deg_s[s];
            float rs = ds > 0.f ? rsqrtf(ds) : 0.f;
            s_src[t] = s;
            s_nrm[t] = w[e] * rs;
        }
        __syncthreads();
        int m = end - base; if (m > 128) m = 128;
        #pragma unroll 4
        for (int jj = 0; jj < m; jj++) {
            acc += s_nrm[jj] * h1[s_src[jj] * H + t];
        }
        __syncthreads();
    }
    c1out[d * H + t] = fmaxf(acc * rdd + bias[t], 0.f);
}

// ------------------- cf aggregation -> f2 -> fused mean-pool accumulation
// block = 64 consecutive fact dst nodes, 128 threads (thread = column)
__global__ __launch_bounds__(128) void agg_cf_pool_kernel(const int* __restrict__ off,
                                                          const int* __restrict__ elist,
                                                          const int* __restrict__ srcs,
                                                          const float* __restrict__ w,
                                                          const float* __restrict__ deg_s,
                                                          const float* __restrict__ deg_d,
                                                          const float* __restrict__ h2,
                                                          const float* __restrict__ bias,
                                                          const int* __restrict__ batch,
                                                          float* __restrict__ pooled,
                                                          float* __restrict__ bcnt) {
    int t = threadIdx.x;
    int f0 = blockIdx.x * 64;
    int f1 = f0 + 64; if (f1 > NF) f1 = NF;
    float bval = bias[t];
    int   cur_b = -1;
    float accp  = 0.f;
    int   runc  = 0;
    for (int f = f0; f < f1; f++) {
        int start = off[f], end = off[f + 1];
        float dd  = deg_d[f];
        float rdd = dd > 0.f ? rsqrtf(dd) : 0.f;
        float acc = 0.f;
        for (int j = start; j < end; j++) {
            int e = elist[j];
            int s = srcs[e];
            float ds = deg_s[s];
            float rs = ds > 0.f ? rsqrtf(ds) : 0.f;
            acc += (w[e] * rs) * h2[s * H + t];
        }
        float val = fmaxf(acc * rdd + bval, 0.f);
        int b = batch[f];                 // uniform across block
        if (b != cur_b) {
            if (cur_b >= 0) {
                atomicAdd(&pooled[cur_b * H + t], accp);
                if (t == 0) atomicAdd(&bcnt[cur_b], (float)runc);
            }
            cur_b = b; accp = 0.f; runc = 0;
        }
        accp += val;
        runc++;
    }
    if (cur_b >= 0) {
        atomicAdd(&pooled[cur_b * H + t], accp);
        if (t == 0) atomicAdd(&bcnt[cur_b], (float)runc);
    }
}

// ----------------------------------------------------------- classifier
__global__ void final_kernel(const float* __restrict__ pooled,
                             const float* __restrict__ bcnt,
                             const float* __restrict__ Wc,
                             const float* __restrict__ bc,
                             float* __restrict__ out) {
    int b = threadIdx.x;  // 256 threads, 1 block
    float sum = 0.f;
    #pragma unroll 8
    for (int k = 0; k < H; k++) sum += pooled[b * H + k] * Wc[k];
    float c = bcnt[b]; if (c < 1.f) c = 1.f;
    out[b] = sum / c + bc[0];
}

// ================================================================ launch
extern "C" void kernel_launch(void* const* d_in, const int* in_sizes, int n_in,
                              void* d_out, int out_size, void* d_ws, size_t ws_size,
                              hipStream_t stream) {
    const float* x_fact = (const float*)d_in[0];
    const float* ea_fc  = (const float*)d_in[2];
    const float* ea_cf  = (const float*)d_in[3];
    const int*   fc_src = (const int*)d_in[4];
    const int*   fc_dst = (const int*)d_in[5];
    const int*   cf_src = (const int*)d_in[6];
    const int*   cf_dst = (const int*)d_in[7];
    const int*   batch  = (const int*)d_in[8];
    const float* Wm     = (const float*)d_in[9];
    const float* bm     = (const float*)d_in[10];
    const float* W1_fc  = (const float*)d_in[11];
    const float* b1_fc  = (const float*)d_in[12];
    const float* W2_cf  = (const float*)d_in[17];
    const float* b2_cf  = (const float*)d_in[18];
    const float* Wc     = (const float*)d_in[19];
    const float* bc     = (const float*)d_in[20];
    float* out = (float*)d_out;

    char* wsb = (char*)d_ws;
    size_t o = 0;
    auto take = [&](size_t bytes) -> char* {
        char* p = wsb + o;
        o += (bytes + 255) & ~(size_t)255;
        return p;
    };

    // ---- zero-initialized region (contiguous) ----
    size_t zr_floats = (size_t)NF + NC + NC + NF   // degrees
                     + (size_t)NC + NF             // counts (int, 0 bits == 0.0f)
                     + (size_t)B * H + B;          // pooled sums + counts
    char* zbase = take(zr_floats * 4);
    float* deg_s_fc = (float*)zbase;
    float* deg_d_fc = deg_s_fc + NF;
    float* deg_s_cf = deg_d_fc + NC;
    float* deg_d_cf = deg_s_cf + NC;
    int*   cnt_fc   = (int*)(deg_d_cf + NF);
    int*   cnt_cf   = cnt_fc + NC;
    float* pooled   = (float*)(cnt_cf + NF);
    float* bcnt     = pooled + (size_t)B * H;

    int*   off_fc   = (int*)take((NC + 1) * 4);
    int*   cur_fc   = (int*)take((size_t)NC * 4);
    int*   off_cf   = (int*)take((NF + 1) * 4);
    int*   cur_cf   = (int*)take((size_t)NF * 4);
    float* w_fc     = (float*)take((size_t)EF * 4);
    float* w_cf     = (float*)take((size_t)EF * 4);
    int*   elist_fc = (int*)take((size_t)EF * 4);
    int*   elist_cf = (int*)take((size_t)EF * 4);
    float* h1       = (float*)take((size_t)NF * H * 4);
    float* c1       = (float*)take((size_t)NC * H * 4);
    float* h2       = (float*)take((size_t)NC * H * 4);

    int zn = (int)zr_floats;
    zero_kernel<<<(zn + 255) / 256, 256, 0, stream>>>((float*)zbase, zn);

    int eblocks = (EF + 255) / 256;
    gate_deg_kernel<<<eblocks, 256, 0, stream>>>(ea_fc, fc_src, fc_dst, Wm, bm,
                                                 w_fc, deg_s_fc, deg_d_fc, cnt_fc, EF);
    gate_deg_kernel<<<eblocks, 256, 0, stream>>>(ea_cf, cf_src, cf_dst, Wm, bm,
                                                 w_cf, deg_s_cf, deg_d_cf, cnt_cf, EF);

    scan_kernel<<<2, 1024, 0, stream>>>(cnt_fc, off_fc, cur_fc, NC,
                                        cnt_cf, off_cf, cur_cf, NF);

    fill_kernel<<<eblocks, 256, 0, stream>>>(fc_dst, cur_fc, elist_fc, EF);
    fill_kernel<<<eblocks, 256, 0, stream>>>(cf_dst, cur_cf, elist_cf, EF);

    // h1 = x_fact @ W1_fc   [100000 x 768] @ [768 x 128]
    gemm_kernel<<<(NF + BM - 1) / BM, 256, 0, stream>>>(x_fact, W1_fc, h1, NF, DF);

    // c1 = relu(aggregate + b1_fc)
    agg_fc_kernel<<<NC, 128, 0, stream>>>(off_fc, elist_fc, fc_src, w_fc,
                                          deg_s_fc, deg_d_fc, h1, b1_fc, c1);

    // h2 = c1 @ W2_cf   [10000 x 128] @ [128 x 128]
    gemm_kernel<<<(NC + BM - 1) / BM, 256, 0, stream>>>(c1, W2_cf, h2, NC, H);

    // f2 aggregation fused with mean-pool accumulation
    agg_cf_pool_kernel<<<(NF + 63) / 64, 128, 0, stream>>>(off_cf, elist_cf, cf_src, w_cf,
                                                           deg_s_cf, deg_d_cf, h2, b2_cf,
                                                           batch, pooled, bcnt);

    final_kernel<<<1, 256, 0, stream>>>(pooled, bcnt, Wc, bc, out);
}

// Round 2
// 1164.019 us; speedup vs baseline: 1.7156x; 1.7156x over previous
//
#include <hip/hip_runtime.h>
#include <hip/hip_bf16.h>

#define NF 100000
#define NC 10000
#define EF 800000
#define DF 768
#define DC 128
#define H  128
#define B  256

typedef __bf16 bf16x8 __attribute__((ext_vector_type(8)));
typedef __bf16 bf16x4 __attribute__((ext_vector_type(4)));
typedef float  f32x4  __attribute__((ext_vector_type(4)));

// ---------------------------------------------------------------- zero
__global__ void zero_kernel(float* p, int n) {
    int i = blockIdx.x * 256 + threadIdx.x;
    if (i < n) p[i] = 0.0f;
}

// ----------------------------------------------- weight prepack (bf16 split)
// W1[DF x H] -> b1h/b1l [H x DF] (n-major);  W2[H x H] -> b2h/b2l [H x H]
__global__ void prepack_kernel(const float* __restrict__ W1,
                               const float* __restrict__ W2,
                               __bf16* __restrict__ b1h, __bf16* __restrict__ b1l,
                               __bf16* __restrict__ b2h, __bf16* __restrict__ b2l) {
    int idx = blockIdx.x * 256 + threadIdx.x;
    const int N1 = DF * H;
    if (idx < N1) {
        int k = idx >> 7, n = idx & 127;
        float x = W1[idx];
        __bf16 h = (__bf16)x;
        b1h[n * DF + k] = h;
        b1l[n * DF + k] = (__bf16)(x - (float)h);
    } else if (idx < N1 + H * H) {
        int j = idx - N1;
        int k = j >> 7, n = j & 127;
        float x = W2[j];
        __bf16 h = (__bf16)x;
        b2h[n * H + k] = h;
        b2l[n * H + k] = (__bf16)(x - (float)h);
    }
}

// ---------------------------------------------------- edge gate + degrees
__global__ void gate_deg_kernel(const float* __restrict__ ea,
                                const int* __restrict__ src,
                                const int* __restrict__ dst,
                                const float* __restrict__ Wm,
                                const float* __restrict__ bm,
                                float* __restrict__ w_out,
                                float* __restrict__ deg_s,
                                float* __restrict__ deg_d,
                                int* __restrict__ cnt_dst,
                                int n_edges) {
    int e = blockIdx.x * 256 + threadIdx.x;
    if (e >= n_edges) return;
    float2 a = ((const float2*)ea)[e];
    float z = a.x * Wm[0] + a.y * Wm[1] + bm[0];
    float w = 1.0f / (1.0f + expf(-z));
    w_out[e] = w;
    atomicAdd(&deg_s[src[e]], w);
    atomicAdd(&deg_d[dst[e]], w);
    atomicAdd(&cnt_dst[dst[e]], 1);
}

// ------------------------------------------------- hierarchical scan
#define SCAN_CHUNK 2048
__global__ __launch_bounds__(256) void scan_p1(const int* __restrict__ cnt, int n,
                                               int* __restrict__ bsum) {
    __shared__ int red[256];
    int b = blockIdx.x, t = threadIdx.x;
    int base = b * SCAN_CHUNK;
    int s = 0;
    #pragma unroll
    for (int i = 0; i < 8; i++) {
        int idx = base + t + i * 256;
        if (idx < n) s += cnt[idx];
    }
    red[t] = s;
    __syncthreads();
    for (int o = 128; o > 0; o >>= 1) {
        if (t < o) red[t] += red[t + o];
        __syncthreads();
    }
    if (t == 0) bsum[b] = red[0];
}

// single wave (64 threads): exclusive scan of bsum[0..g), write off[n]=total
__global__ void scan_p2(int* __restrict__ bsum, int g, int* __restrict__ off, int n) {
    int t = threadIdx.x;
    int own = (t < g) ? bsum[t] : 0;
    int v = own;
    #pragma unroll
    for (int o = 1; o < 64; o <<= 1) {
        int u = __shfl_up(v, o, 64);
        if (t >= o) v += u;
    }
    if (t < g) bsum[t] = v - own;
    if (t == 63) off[n] = v;
}

__global__ __launch_bounds__(256) void scan_p3(const int* __restrict__ cnt, int n,
                                               const int* __restrict__ bsum,
                                               int* __restrict__ off, int* __restrict__ cur) {
    int b = blockIdx.x, t = threadIdx.x;
    int base = b * SCAN_CHUNK + t * 8;
    int v[8];
    int s = 0;
    #pragma unroll
    for (int i = 0; i < 8; i++) {
        int idx = base + i;
        v[i] = (idx < n) ? cnt[idx] : 0;
        s += v[i];
    }
    int lane = t & 63, wv = t >> 6;
    int incl = s;
    #pragma unroll
    for (int o = 1; o < 64; o <<= 1) {
        int u = __shfl_up(incl, o, 64);
        if (lane >= o) incl += u;
    }
    __shared__ int wtot[4];
    if (lane == 63) wtot[wv] = incl;
    __syncthreads();
    int woff = 0;
    for (int i = 0; i < wv; i++) woff += wtot[i];
    int run = incl - s + woff + bsum[b];
    #pragma unroll
    for (int i = 0; i < 8; i++) {
        int idx = base + i;
        if (idx < n) {
            off[idx] = run;
            cur[idx] = run;
            run += v[i];
        }
    }
}

// ------------------------------------------------------------- CSR fill
__global__ void fill_kernel(const int* __restrict__ dst,
                            int* __restrict__ cur,
                            int* __restrict__ elist, int n_edges) {
    int e = blockIdx.x * 256 + threadIdx.x;
    if (e >= n_edges) return;
    int p = atomicAdd(&cur[dst[e]], 1);
    elist[p] = e;
}

// ----------------------------------------------------- MFMA split-bf16 GEMM
// C[M x 128] = A[M x K] (fp32) @ B[K x 128], B prepacked transposed bf16 hi/lo.
// 3-pass split: AhiBhi + AhiBlo + AloBhi, fp32 accumulate.
__global__ __launch_bounds__(256) void gemm_mfma_kernel(const float* __restrict__ A,
                                                        const __bf16* __restrict__ Bth,
                                                        const __bf16* __restrict__ Btl,
                                                        float* __restrict__ C,
                                                        int M, int K) {
    // stride 40 bf16 = 80 B: multiple of 16 B (ds_read_b128 ok), bank-spread
    __shared__ __attribute__((aligned(16))) __bf16 As_hi[128][40];
    __shared__ __attribute__((aligned(16))) __bf16 As_lo[128][40];
    __shared__ __attribute__((aligned(16))) __bf16 Bs_hi[128][40];
    __shared__ __attribute__((aligned(16))) __bf16 Bs_lo[128][40];
    int t = threadIdx.x;
    int lane = t & 63, wave = t >> 6;
    int wm = wave & 1, wn = wave >> 1;
    int row0 = blockIdx.x * 128;
    f32x4 acc[4][4] = {};

    for (int k0 = 0; k0 < K; k0 += 32) {
        // stage A (128 rows x 32 k, fp32 -> hi/lo bf16)
        #pragma unroll
        for (int i = 0; i < 4; i++) {
            int c = t + i * 256;
            int r = c >> 3, c4 = c & 7;
            float4 v = make_float4(0.f, 0.f, 0.f, 0.f);
            int gr = row0 + r;
            if (gr < M) v = *(const float4*)&A[(size_t)gr * K + k0 + c4 * 4];
            float xs0 = v.x, xs1 = v.y, xs2 = v.z, xs3 = v.w;
            bf16x4 hv, lv;
            __bf16 h0 = (__bf16)xs0; hv[0] = h0; lv[0] = (__bf16)(xs0 - (float)h0);
            __bf16 h1 = (__bf16)xs1; hv[1] = h1; lv[1] = (__bf16)(xs1 - (float)h1);
            __bf16 h2 = (__bf16)xs2; hv[2] = h2; lv[2] = (__bf16)(xs2 - (float)h2);
            __bf16 h3 = (__bf16)xs3; hv[3] = h3; lv[3] = (__bf16)(xs3 - (float)h3);
            *(bf16x4*)&As_hi[r][c4 * 4] = hv;
            *(bf16x4*)&As_lo[r][c4 * 4] = lv;
        }
        // stage B (128 n x 32 k, prepacked bf16)
        #pragma unroll
        for (int i = 0; i < 2; i++) {
            int c = t + i * 256;
            int n = c >> 2, koff = (c & 3) * 8;
            *(int4*)&Bs_hi[n][koff] = *(const int4*)&Bth[(size_t)n * K + k0 + koff];
            *(int4*)&Bs_lo[n][koff] = *(const int4*)&Btl[(size_t)n * K + k0 + koff];
        }
        __syncthreads();

        bf16x8 ah[4], al[4], bh[4], bl[4];
        int mrow = wm * 64 + (lane & 15);
        int nrow = wn * 64 + (lane & 15);
        int kq = (lane >> 4) * 8;
        #pragma unroll
        for (int mt = 0; mt < 4; mt++) {
            ah[mt] = *(const bf16x8*)&As_hi[mrow + mt * 16][kq];
            al[mt] = *(const bf16x8*)&As_lo[mrow + mt * 16][kq];
        }
        #pragma unroll
        for (int nt = 0; nt < 4; nt++) {
            bh[nt] = *(const bf16x8*)&Bs_hi[nrow + nt * 16][kq];
            bl[nt] = *(const bf16x8*)&Bs_lo[nrow + nt * 16][kq];
        }
        #pragma unroll
        for (int mt = 0; mt < 4; mt++) {
            #pragma unroll
            for (int nt = 0; nt < 4; nt++) {
                acc[mt][nt] = __builtin_amdgcn_mfma_f32_16x16x32_bf16(ah[mt], bh[nt], acc[mt][nt], 0, 0, 0);
                acc[mt][nt] = __builtin_amdgcn_mfma_f32_16x16x32_bf16(ah[mt], bl[nt], acc[mt][nt], 0, 0, 0);
                acc[mt][nt] = __builtin_amdgcn_mfma_f32_16x16x32_bf16(al[mt], bh[nt], acc[mt][nt], 0, 0, 0);
            }
        }
        __syncthreads();
    }
    // epilogue: C/D layout col=lane&15, row=(lane>>4)*4+r
    #pragma unroll
    for (int mt = 0; mt < 4; mt++) {
        int rbase = row0 + wm * 64 + mt * 16 + (lane >> 4) * 4;
        #pragma unroll
        for (int nt = 0; nt < 4; nt++) {
            int col = wn * 64 + nt * 16 + (lane & 15);
            #pragma unroll
            for (int r = 0; r < 4; r++) {
                int gr = rbase + r;
                if (gr < M) C[(size_t)gr * 128 + col] = acc[mt][nt][r];
            }
        }
    }
}

// ------------------------------------------- fc aggregation -> c1 (relu+bias)
// one block (128 threads) per company dst node; edge window staged in LDS
__global__ __launch_bounds__(128) void agg_fc_kernel(const int* __restrict__ off,
                                                     const int* __restrict__ elist,
                                                     const int* __restrict__ srcs,
                                                     const float* __restrict__ w,
                                                     const float* __restrict__ deg_s,
                                                     const float* __restrict__ deg_d,
                                                     const float* __restrict__ h1,
                                                     const float* __restrict__ bias,
                                                     float* __restrict__ c1out) {
    int d = blockIdx.x;
    int t = threadIdx.x;
    int start = off[d], end = off[d + 1];
    __shared__ int   s_src[128];
    __shared__ float s_nrm[128];
    float dd  = deg_d[d];
    float rdd = dd > 0.f ? rsqrtf(dd) : 0.f;
    float acc = 0.f;
    for (int base = start; base < end; base += 128) {
        int j = base + t;
        if (j < end) {
            int e = elist[j];
            int s = srcs[e];
            float ds = deg_s[s];
            float rs = ds > 0.f ? rsqrtf(ds) : 0.f;
            s_src[t] = s;
            s_nrm[t] = w[e] * rs;
        }
        __syncthreads();
        int m = end - base; if (m > 128) m = 128;
        #pragma unroll 4
        for (int jj = 0; jj < m; jj++) {
            acc += s_nrm[jj] * h1[s_src[jj] * H + t];
        }
        __syncthreads();
    }
    c1out[d * H + t] = fmaxf(acc * rdd + bias[t], 0.f);
}

// ------------------- cf aggregation -> f2 -> fused mean-pool accumulation
// block = 8 fact dst nodes (NF % 8 == 0), 128 threads (thread = column);
// edge windows of 128 staged cooperatively in LDS.
#define FPB 8
__global__ __launch_bounds__(128) void agg_cf_pool_kernel(const int* __restrict__ off,
                                                          const int* __restrict__ elist,
                                                          const int* __restrict__ srcs,
                                                          const float* __restrict__ w,
                                                          const float* __restrict__ deg_s,
                                                          const float* __restrict__ deg_d,
                                                          const float* __restrict__ h2,
                                                          const float* __restrict__ bias,
                                                          const int* __restrict__ batch,
                                                          float* __restrict__ pooled,
                                                          float* __restrict__ bcnt) {
    int t = threadIdx.x;
    int f0 = blockIdx.x * FPB;
    __shared__ int   s_off[FPB + 1];
    __shared__ int   s_batch[FPB];
    __shared__ float s_rdd[FPB];
    if (t <= FPB) s_off[t] = off[f0 + t];
    if (t < FPB) {
        s_batch[t] = batch[f0 + t];
        float dd = deg_d[f0 + t];
        s_rdd[t] = dd > 0.f ? rsqrtf(dd) : 0.f;
    }
    __syncthreads();
    int start = s_off[0], end = s_off[FPB];
    float acc[FPB] = {};
    __shared__ int   s_src[128];
    __shared__ float s_nrm[128];
    for (int base = start; base < end; base += 128) {
        int j = base + t;
        if (j < end) {
            int e = elist[j];
            int s = srcs[e];
            float ds = deg_s[s];
            s_src[t] = s;
            s_nrm[t] = w[e] * (ds > 0.f ? rsqrtf(ds) : 0.f);
        }
        __syncthreads();
        int wend = end < base + 128 ? end : base + 128;
        #pragma unroll
        for (int f = 0; f < FPB; f++) {
            int lo = s_off[f] > base ? s_off[f] : base;
            int hi = s_off[f + 1] < wend ? s_off[f + 1] : wend;
            for (int j2 = lo - base; j2 < hi - base; j2++)
                acc[f] += s_nrm[j2] * h2[s_src[j2] * H + t];
        }
        __syncthreads();
    }
    // fused mean-pool accumulation (batch sorted -> run detection)
    float bval = bias[t];
    int cur_b = -1;
    float accp = 0.f;
    int runc = 0;
    #pragma unroll
    for (int f = 0; f < FPB; f++) {
        float val = fmaxf(acc[f] * s_rdd[f] + bval, 0.f);
        int b = s_batch[f];
        if (b != cur_b) {
            if (cur_b >= 0) {
                atomicAdd(&pooled[cur_b * H + t], accp);
                if (t == 0) atomicAdd(&bcnt[cur_b], (float)runc);
            }
            cur_b = b; accp = 0.f; runc = 0;
        }
        accp += val;
        runc++;
    }
    if (cur_b >= 0) {
        atomicAdd(&pooled[cur_b * H + t], accp);
        if (t == 0) atomicAdd(&bcnt[cur_b], (float)runc);
    }
}

// ----------------------------------------------------------- classifier
__global__ void final_kernel(const float* __restrict__ pooled,
                             const float* __restrict__ bcnt,
                             const float* __restrict__ Wc,
                             const float* __restrict__ bc,
                             float* __restrict__ out) {
    int b = threadIdx.x;  // 256 threads, 1 block
    float sum = 0.f;
    #pragma unroll 8
    for (int k = 0; k < H; k++) sum += pooled[b * H + k] * Wc[k];
    float c = bcnt[b]; if (c < 1.f) c = 1.f;
    out[b] = sum / c + bc[0];
}

// ================================================================ launch
extern "C" void kernel_launch(void* const* d_in, const int* in_sizes, int n_in,
                              void* d_out, int out_size, void* d_ws, size_t ws_size,
                              hipStream_t stream) {
    const float* x_fact = (const float*)d_in[0];
    const float* ea_fc  = (const float*)d_in[2];
    const float* ea_cf  = (const float*)d_in[3];
    const int*   fc_src = (const int*)d_in[4];
    const int*   fc_dst = (const int*)d_in[5];
    const int*   cf_src = (const int*)d_in[6];
    const int*   cf_dst = (const int*)d_in[7];
    const int*   batch  = (const int*)d_in[8];
    const float* Wm     = (const float*)d_in[9];
    const float* bm     = (const float*)d_in[10];
    const float* W1_fc  = (const float*)d_in[11];
    const float* b1_fc  = (const float*)d_in[12];
    const float* W2_cf  = (const float*)d_in[17];
    const float* b2_cf  = (const float*)d_in[18];
    const float* Wc     = (const float*)d_in[19];
    const float* bc     = (const float*)d_in[20];
    float* out = (float*)d_out;

    char* wsb = (char*)d_ws;
    size_t o = 0;
    auto take = [&](size_t bytes) -> char* {
        char* p = wsb + o;
        o += (bytes + 255) & ~(size_t)255;
        return p;
    };

    // ---- zero-initialized region (contiguous) ----
    size_t zr_floats = (size_t)NF + NC + NC + NF
                     + (size_t)NC + NF
                     + (size_t)B * H + B;
    char* zbase = take(zr_floats * 4);
    float* deg_s_fc = (float*)zbase;
    float* deg_d_fc = deg_s_fc + NF;
    float* deg_s_cf = deg_d_fc + NC;
    float* deg_d_cf = deg_s_cf + NC;
    int*   cnt_fc   = (int*)(deg_d_cf + NF);
    int*   cnt_cf   = cnt_fc + NC;
    float* pooled   = (float*)(cnt_cf + NF);
    float* bcnt     = pooled + (size_t)B * H;

    int*   off_fc   = (int*)take((NC + 1) * 4);
    int*   cur_fc   = (int*)take((size_t)NC * 4);
    int*   off_cf   = (int*)take((NF + 1) * 4);
    int*   cur_cf   = (int*)take((size_t)NF * 4);
    int*   bsum_fc  = (int*)take(64 * 4);
    int*   bsum_cf  = (int*)take(64 * 4);
    float* w_fc     = (float*)take((size_t)EF * 4);
    float* w_cf     = (float*)take((size_t)EF * 4);
    int*   elist_fc = (int*)take((size_t)EF * 4);
    int*   elist_cf = (int*)take((size_t)EF * 4);
    float* h1       = (float*)take((size_t)NF * H * 4);
    float* c1       = (float*)take((size_t)NC * H * 4);
    float* h2       = (float*)take((size_t)NC * H * 4);
    __bf16* b1h     = (__bf16*)take((size_t)DF * H * 2);
    __bf16* b1l     = (__bf16*)take((size_t)DF * H * 2);
    __bf16* b2h     = (__bf16*)take((size_t)H * H * 2);
    __bf16* b2l     = (__bf16*)take((size_t)H * H * 2);

    int zn = (int)zr_floats;
    zero_kernel<<<(zn + 255) / 256, 256, 0, stream>>>((float*)zbase, zn);

    prepack_kernel<<<(DF * H + H * H + 255) / 256, 256, 0, stream>>>(
        W1_fc, W2_cf, b1h, b1l, b2h, b2l);

    int eblocks = (EF + 255) / 256;
    gate_deg_kernel<<<eblocks, 256, 0, stream>>>(ea_fc, fc_src, fc_dst, Wm, bm,
                                                 w_fc, deg_s_fc, deg_d_fc, cnt_fc, EF);
    gate_deg_kernel<<<eblocks, 256, 0, stream>>>(ea_cf, cf_src, cf_dst, Wm, bm,
                                                 w_cf, deg_s_cf, deg_d_cf, cnt_cf, EF);

    int g_fc = (NC + SCAN_CHUNK - 1) / SCAN_CHUNK;   // 5
    int g_cf = (NF + SCAN_CHUNK - 1) / SCAN_CHUNK;   // 49
    scan_p1<<<g_fc, 256, 0, stream>>>(cnt_fc, NC, bsum_fc);
    scan_p1<<<g_cf, 256, 0, stream>>>(cnt_cf, NF, bsum_cf);
    scan_p2<<<1, 64, 0, stream>>>(bsum_fc, g_fc, off_fc, NC);
    scan_p2<<<1, 64, 0, stream>>>(bsum_cf, g_cf, off_cf, NF);
    scan_p3<<<g_fc, 256, 0, stream>>>(cnt_fc, NC, bsum_fc, off_fc, cur_fc);
    scan_p3<<<g_cf, 256, 0, stream>>>(cnt_cf, NF, bsum_cf, off_cf, cur_cf);

    fill_kernel<<<eblocks, 256, 0, stream>>>(fc_dst, cur_fc, elist_fc, EF);
    fill_kernel<<<eblocks, 256, 0, stream>>>(cf_dst, cur_cf, elist_cf, EF);

    // h1 = x_fact @ W1_fc   [100000 x 768] @ [768 x 128]
    gemm_mfma_kernel<<<(NF + 127) / 128, 256, 0, stream>>>(x_fact, b1h, b1l, h1, NF, DF);

    // c1 = relu(aggregate + b1_fc)
    agg_fc_kernel<<<NC, 128, 0, stream>>>(off_fc, elist_fc, fc_src, w_fc,
                                          deg_s_fc, deg_d_fc, h1, b1_fc, c1);

    // h2 = c1 @ W2_cf   [10000 x 128] @ [128 x 128]
    gemm_mfma_kernel<<<(NC + 127) / 128, 256, 0, stream>>>(c1, b2h, b2l, h2, NC, H);

    // f2 aggregation fused with mean-pool accumulation
    agg_cf_pool_kernel<<<NF / FPB, 128, 0, stream>>>(off_cf, elist_cf, cf_src, w_cf,
                                                     deg_s_cf, deg_d_cf, h2, b2_cf,
                                                     batch, pooled, bcnt);

    final_kernel<<<1, 256, 0, stream>>>(pooled, bcnt, Wc, bc, out);
}

// Round 3
// 1048.730 us; speedup vs baseline: 1.9041x; 1.1099x over previous
//
#include <hip/hip_runtime.h>
#include <hip/hip_bf16.h>

#define NF 100000
#define NC 10000
#define EF 800000
#define DF 768
#define DC 128
#define H  128
#define B  256

typedef __bf16 bf16x8 __attribute__((ext_vector_type(8)));
typedef float  f32x4  __attribute__((ext_vector_type(4)));

// ---------------------------------------------------------------- zero
__global__ void zero_kernel(float* p, int n) {
    int i = blockIdx.x * 256 + threadIdx.x;
    if (i < n) p[i] = 0.0f;
}

// ----------------------------------------------- weight prepack (bf16 split)
// W1[DF x H] -> b1h/b1l [H x DF] (n-major);  W2[H x H] -> b2h/b2l [H x H]
__global__ void prepack_kernel(const float* __restrict__ W1,
                               const float* __restrict__ W2,
                               __bf16* __restrict__ b1h, __bf16* __restrict__ b1l,
                               __bf16* __restrict__ b2h, __bf16* __restrict__ b2l) {
    int idx = blockIdx.x * 256 + threadIdx.x;
    const int N1 = DF * H;
    if (idx < N1) {
        int k = idx >> 7, n = idx & 127;
        float x = W1[idx];
        __bf16 h = (__bf16)x;
        b1h[n * DF + k] = h;
        b1l[n * DF + k] = (__bf16)(x - (float)h);
    } else if (idx < N1 + H * H) {
        int j = idx - N1;
        int k = j >> 7, n = j & 127;
        float x = W2[j];
        __bf16 h = (__bf16)x;
        b2h[n * H + k] = h;
        b2l[n * H + k] = (__bf16)(x - (float)h);
    }
}

// ---------------------------------------------------- edge gate + degrees
__global__ void gate_deg_kernel(const float* __restrict__ ea,
                                const int* __restrict__ src,
                                const int* __restrict__ dst,
                                const float* __restrict__ Wm,
                                const float* __restrict__ bm,
                                float* __restrict__ w_out,
                                float* __restrict__ deg_s,
                                float* __restrict__ deg_d,
                                int* __restrict__ cnt_dst,
                                int n_edges) {
    int e = blockIdx.x * 256 + threadIdx.x;
    if (e >= n_edges) return;
    float2 a = ((const float2*)ea)[e];
    float z = a.x * Wm[0] + a.y * Wm[1] + bm[0];
    float w = 1.0f / (1.0f + expf(-z));
    w_out[e] = w;
    atomicAdd(&deg_s[src[e]], w);
    atomicAdd(&deg_d[dst[e]], w);
    atomicAdd(&cnt_dst[dst[e]], 1);
}

// ------------------------------------------------- hierarchical scan
#define SCAN_CHUNK 2048
__global__ __launch_bounds__(256) void scan_p1(const int* __restrict__ cnt, int n,
                                               int* __restrict__ bsum) {
    __shared__ int red[256];
    int b = blockIdx.x, t = threadIdx.x;
    int base = b * SCAN_CHUNK;
    int s = 0;
    #pragma unroll
    for (int i = 0; i < 8; i++) {
        int idx = base + t + i * 256;
        if (idx < n) s += cnt[idx];
    }
    red[t] = s;
    __syncthreads();
    for (int o = 128; o > 0; o >>= 1) {
        if (t < o) red[t] += red[t + o];
        __syncthreads();
    }
    if (t == 0) bsum[b] = red[0];
}

__global__ void scan_p2(int* __restrict__ bsum, int g, int* __restrict__ off, int n) {
    int t = threadIdx.x;
    int own = (t < g) ? bsum[t] : 0;
    int v = own;
    #pragma unroll
    for (int o = 1; o < 64; o <<= 1) {
        int u = __shfl_up(v, o, 64);
        if (t >= o) v += u;
    }
    if (t < g) bsum[t] = v - own;
    if (t == 63) off[n] = v;
}

__global__ __launch_bounds__(256) void scan_p3(const int* __restrict__ cnt, int n,
                                               const int* __restrict__ bsum,
                                               int* __restrict__ off, int* __restrict__ cur) {
    int b = blockIdx.x, t = threadIdx.x;
    int base = b * SCAN_CHUNK + t * 8;
    int v[8];
    int s = 0;
    #pragma unroll
    for (int i = 0; i < 8; i++) {
        int idx = base + i;
        v[i] = (idx < n) ? cnt[idx] : 0;
        s += v[i];
    }
    int lane = t & 63, wv = t >> 6;
    int incl = s;
    #pragma unroll
    for (int o = 1; o < 64; o <<= 1) {
        int u = __shfl_up(incl, o, 64);
        if (lane >= o) incl += u;
    }
    __shared__ int wtot[4];
    if (lane == 63) wtot[wv] = incl;
    __syncthreads();
    int woff = 0;
    for (int i = 0; i < wv; i++) woff += wtot[i];
    int run = incl - s + woff + bsum[b];
    #pragma unroll
    for (int i = 0; i < 8; i++) {
        int idx = base + i;
        if (idx < n) {
            off[idx] = run;
            cur[idx] = run;
            run += v[i];
        }
    }
}

// --------------------------------------------- CSR fill with packed records
// pack[p] = {src_as_float_bits, w * rsqrt(deg_s[src])}
__global__ void fill_pack_kernel(const int* __restrict__ src,
                                 const int* __restrict__ dst,
                                 const float* __restrict__ w,
                                 const float* __restrict__ deg_s,
                                 int* __restrict__ cur,
                                 float2* __restrict__ pack, int n_edges) {
    int e = blockIdx.x * 256 + threadIdx.x;
    if (e >= n_edges) return;
    int s = src[e];
    float ds = deg_s[s];
    float nrm = w[e] * (ds > 0.f ? rsqrtf(ds) : 0.f);
    int p = atomicAdd(&cur[dst[e]], 1);
    pack[p] = make_float2(__int_as_float(s), nrm);
}

// ----------------------------------------------------- MFMA split-bf16 GEMM
// Cb[M x 128] (bf16) = A[M x K] (fp32) @ B[K x 128] (prepacked bf16 hi/lo, n-major)
// A loaded directly global->reg (no LDS); B staged in LDS (2-way banks only).
__global__ __launch_bounds__(256) void gemm_dsplit_kernel(const float* __restrict__ A,
                                                          const __bf16* __restrict__ Bth,
                                                          const __bf16* __restrict__ Btl,
                                                          __bf16* __restrict__ Cb,
                                                          int M, int K) {
    __shared__ __attribute__((aligned(16))) __bf16 Bs_hi[128][40];
    __shared__ __attribute__((aligned(16))) __bf16 Bs_lo[128][40];
    int t = threadIdx.x;
    int lane = t & 63, wave = t >> 6;
    int row0 = blockIdx.x * 128;
    int m0 = wave * 32;              // wave's 32-row slice of the 128-row tile
    int mrow = lane & 15;
    int kq = (lane >> 4) * 8;        // k-offset of this lane's fragment
    f32x4 acc[2][8] = {};

    for (int k0 = 0; k0 < K; k0 += 32) {
        __syncthreads();             // prior iter's Bs reads done
        // stage B: 128n x 32k hi+lo (each thread: 2 x 16B per array)
        #pragma unroll
        for (int i = 0; i < 2; i++) {
            int c = t + i * 256;     // 0..511
            int n = c >> 2, ko = (c & 3) * 8;
            *(int4*)&Bs_hi[n][ko] = *(const int4*)&Bth[(size_t)n * K + k0 + ko];
            *(int4*)&Bs_lo[n][ko] = *(const int4*)&Btl[(size_t)n * K + k0 + ko];
        }
        // A fragments: direct global load + in-register hi/lo split
        bf16x8 ah[2], al[2];
        #pragma unroll
        for (int mt = 0; mt < 2; mt++) {
            int gr = row0 + m0 + mt * 16 + mrow;
            float4 v0 = make_float4(0.f,0.f,0.f,0.f), v1 = v0;
            if (gr < M) {
                const float* ap = &A[(size_t)gr * K + k0 + kq];
                v0 = *(const float4*)ap;
                v1 = *(const float4*)(ap + 4);
            }
            float f[8] = {v0.x,v0.y,v0.z,v0.w,v1.x,v1.y,v1.z,v1.w};
            #pragma unroll
            for (int j = 0; j < 8; j++) {
                __bf16 h = (__bf16)f[j];
                ah[mt][j] = h;
                al[mt][j] = (__bf16)(f[j] - (float)h);
            }
        }
        __syncthreads();             // Bs visible
        #pragma unroll
        for (int nt = 0; nt < 8; nt++) {
            int nr = nt * 16 + mrow;
            bf16x8 bh = *(const bf16x8*)&Bs_hi[nr][kq];
            bf16x8 bl = *(const bf16x8*)&Bs_lo[nr][kq];
            #pragma unroll
            for (int mt = 0; mt < 2; mt++) {
                acc[mt][nt] = __builtin_amdgcn_mfma_f32_16x16x32_bf16(ah[mt], bh, acc[mt][nt], 0, 0, 0);
                acc[mt][nt] = __builtin_amdgcn_mfma_f32_16x16x32_bf16(ah[mt], bl, acc[mt][nt], 0, 0, 0);
                acc[mt][nt] = __builtin_amdgcn_mfma_f32_16x16x32_bf16(al[mt], bh, acc[mt][nt], 0, 0, 0);
            }
        }
    }
    // epilogue: C/D layout col=lane&15, row=(lane>>4)*4+r
    #pragma unroll
    for (int mt = 0; mt < 2; mt++) {
        int gr0 = row0 + m0 + mt * 16 + (lane >> 4) * 4;
        #pragma unroll
        for (int nt = 0; nt < 8; nt++) {
            int col = nt * 16 + (lane & 15);
            #pragma unroll
            for (int r = 0; r < 4; r++) {
                int gr = gr0 + r;
                if (gr < M) Cb[(size_t)gr * 128 + col] = (__bf16)acc[mt][nt][r];
            }
        }
    }
}

// ------------------------------------------- fc aggregation -> c1 (relu+bias)
// one block (128 threads) per company dst; packed records, bf16 h1
__global__ __launch_bounds__(128) void agg_fc_kernel(const int* __restrict__ off,
                                                     const float2* __restrict__ pack,
                                                     const float* __restrict__ deg_d,
                                                     const __bf16* __restrict__ h1b,
                                                     const float* __restrict__ bias,
                                                     float* __restrict__ c1out) {
    int d = blockIdx.x;
    int t = threadIdx.x;
    int start = off[d], end = off[d + 1];
    __shared__ float2 s_e[128];
    float dd  = deg_d[d];
    float rdd = dd > 0.f ? rsqrtf(dd) : 0.f;
    float acc = 0.f;
    for (int base = start; base < end; base += 128) {
        int j = base + t;
        if (j < end) s_e[t] = pack[j];
        __syncthreads();
        int m = end - base; if (m > 128) m = 128;
        #pragma unroll 4
        for (int jj = 0; jj < m; jj++) {
            float2 p = s_e[jj];
            int s = __float_as_int(p.x);
            acc += p.y * (float)h1b[s * H + t];
        }
        __syncthreads();
    }
    c1out[d * H + t] = fmaxf(acc * rdd + bias[t], 0.f);
}

// ------------------- cf aggregation -> f2 -> fused mean-pool accumulation
#define FPB 8
__global__ __launch_bounds__(128) void agg_cf_pool_kernel(const int* __restrict__ off,
                                                          const float2* __restrict__ pack,
                                                          const float* __restrict__ deg_d,
                                                          const __bf16* __restrict__ h2b,
                                                          const float* __restrict__ bias,
                                                          const int* __restrict__ batch,
                                                          float* __restrict__ pooled,
                                                          float* __restrict__ bcnt) {
    int t = threadIdx.x;
    int f0 = blockIdx.x * FPB;
    __shared__ int   s_off[FPB + 1];
    __shared__ int   s_batch[FPB];
    __shared__ float s_rdd[FPB];
    if (t <= FPB) s_off[t] = off[f0 + t];
    if (t < FPB) {
        s_batch[t] = batch[f0 + t];
        float dd = deg_d[f0 + t];
        s_rdd[t] = dd > 0.f ? rsqrtf(dd) : 0.f;
    }
    __syncthreads();
    int start = s_off[0], end = s_off[FPB];
    float acc[FPB] = {};
    __shared__ float2 s_e[128];
    for (int base = start; base < end; base += 128) {
        int j = base + t;
        if (j < end) s_e[t] = pack[j];
        __syncthreads();
        int wend = end < base + 128 ? end : base + 128;
        #pragma unroll
        for (int f = 0; f < FPB; f++) {
            int lo = s_off[f] > base ? s_off[f] : base;
            int hi = s_off[f + 1] < wend ? s_off[f + 1] : wend;
            for (int j2 = lo - base; j2 < hi - base; j2++) {
                float2 p = s_e[j2];
                int s = __float_as_int(p.x);
                acc[f] += p.y * (float)h2b[s * H + t];
            }
        }
        __syncthreads();
    }
    float bval = bias[t];
    int cur_b = -1;
    float accp = 0.f;
    int runc = 0;
    #pragma unroll
    for (int f = 0; f < FPB; f++) {
        float val = fmaxf(acc[f] * s_rdd[f] + bval, 0.f);
        int b = s_batch[f];
        if (b != cur_b) {
            if (cur_b >= 0) {
                atomicAdd(&pooled[cur_b * H + t], accp);
                if (t == 0) atomicAdd(&bcnt[cur_b], (float)runc);
            }
            cur_b = b; accp = 0.f; runc = 0;
        }
        accp += val;
        runc++;
    }
    if (cur_b >= 0) {
        atomicAdd(&pooled[cur_b * H + t], accp);
        if (t == 0) atomicAdd(&bcnt[cur_b], (float)runc);
    }
}

// ----------------------------------------------------------- classifier
__global__ void final_kernel(const float* __restrict__ pooled,
                             const float* __restrict__ bcnt,
                             const float* __restrict__ Wc,
                             const float* __restrict__ bc,
                             float* __restrict__ out) {
    int b = threadIdx.x;
    float sum = 0.f;
    #pragma unroll 8
    for (int k = 0; k < H; k++) sum += pooled[b * H + k] * Wc[k];
    float c = bcnt[b]; if (c < 1.f) c = 1.f;
    out[b] = sum / c + bc[0];
}

// ================================================================ launch
extern "C" void kernel_launch(void* const* d_in, const int* in_sizes, int n_in,
                              void* d_out, int out_size, void* d_ws, size_t ws_size,
                              hipStream_t stream) {
    const float* x_fact = (const float*)d_in[0];
    const float* ea_fc  = (const float*)d_in[2];
    const float* ea_cf  = (const float*)d_in[3];
    const int*   fc_src = (const int*)d_in[4];
    const int*   fc_dst = (const int*)d_in[5];
    const int*   cf_src = (const int*)d_in[6];
    const int*   cf_dst = (const int*)d_in[7];
    const int*   batch  = (const int*)d_in[8];
    const float* Wm     = (const float*)d_in[9];
    const float* bm     = (const float*)d_in[10];
    const float* W1_fc  = (const float*)d_in[11];
    const float* b1_fc  = (const float*)d_in[12];
    const float* W2_cf  = (const float*)d_in[17];
    const float* b2_cf  = (const float*)d_in[18];
    const float* Wc     = (const float*)d_in[19];
    const float* bc     = (const float*)d_in[20];
    float* out = (float*)d_out;

    char* wsb = (char*)d_ws;
    size_t o = 0;
    auto take = [&](size_t bytes) -> char* {
        char* p = wsb + o;
        o += (bytes + 255) & ~(size_t)255;
        return p;
    };

    // ---- zero-initialized region (contiguous) ----
    size_t zr_floats = (size_t)NF + NC + NC + NF
                     + (size_t)NC + NF
                     + (size_t)B * H + B;
    char* zbase = take(zr_floats * 4);
    float* deg_s_fc = (float*)zbase;
    float* deg_d_fc = deg_s_fc + NF;
    float* deg_s_cf = deg_d_fc + NC;
    float* deg_d_cf = deg_s_cf + NC;
    int*   cnt_fc   = (int*)(deg_d_cf + NF);
    int*   cnt_cf   = cnt_fc + NC;
    float* pooled   = (float*)(cnt_cf + NF);
    float* bcnt     = pooled + (size_t)B * H;

    int*   off_fc   = (int*)take((NC + 1) * 4);
    int*   cur_fc   = (int*)take((size_t)NC * 4);
    int*   off_cf   = (int*)take((NF + 1) * 4);
    int*   cur_cf   = (int*)take((size_t)NF * 4);
    int*   bsum_fc  = (int*)take(64 * 4);
    int*   bsum_cf  = (int*)take(64 * 4);
    float* w_fc     = (float*)take((size_t)EF * 4);
    float* w_cf     = (float*)take((size_t)EF * 4);
    float2* pack_fc = (float2*)take((size_t)EF * 8);
    float2* pack_cf = (float2*)take((size_t)EF * 8);
    __bf16* h1b     = (__bf16*)take((size_t)NF * H * 2);
    float*  c1      = (float*)take((size_t)NC * H * 4);
    __bf16* h2b     = (__bf16*)take((size_t)NC * H * 2);
    __bf16* b1h     = (__bf16*)take((size_t)DF * H * 2);
    __bf16* b1l     = (__bf16*)take((size_t)DF * H * 2);
    __bf16* b2h     = (__bf16*)take((size_t)H * H * 2);
    __bf16* b2l     = (__bf16*)take((size_t)H * H * 2);

    int zn = (int)zr_floats;
    zero_kernel<<<(zn + 255) / 256, 256, 0, stream>>>((float*)zbase, zn);

    prepack_kernel<<<(DF * H + H * H + 255) / 256, 256, 0, stream>>>(
        W1_fc, W2_cf, b1h, b1l, b2h, b2l);

    int eblocks = (EF + 255) / 256;
    gate_deg_kernel<<<eblocks, 256, 0, stream>>>(ea_fc, fc_src, fc_dst, Wm, bm,
                                                 w_fc, deg_s_fc, deg_d_fc, cnt_fc, EF);
    gate_deg_kernel<<<eblocks, 256, 0, stream>>>(ea_cf, cf_src, cf_dst, Wm, bm,
                                                 w_cf, deg_s_cf, deg_d_cf, cnt_cf, EF);

    int g_fc = (NC + SCAN_CHUNK - 1) / SCAN_CHUNK;   // 5
    int g_cf = (NF + SCAN_CHUNK - 1) / SCAN_CHUNK;   // 49
    scan_p1<<<g_fc, 256, 0, stream>>>(cnt_fc, NC, bsum_fc);
    scan_p1<<<g_cf, 256, 0, stream>>>(cnt_cf, NF, bsum_cf);
    scan_p2<<<1, 64, 0, stream>>>(bsum_fc, g_fc, off_fc, NC);
    scan_p2<<<1, 64, 0, stream>>>(bsum_cf, g_cf, off_cf, NF);
    scan_p3<<<g_fc, 256, 0, stream>>>(cnt_fc, NC, bsum_fc, off_fc, cur_fc);
    scan_p3<<<g_cf, 256, 0, stream>>>(cnt_cf, NF, bsum_cf, off_cf, cur_cf);

    fill_pack_kernel<<<eblocks, 256, 0, stream>>>(fc_src, fc_dst, w_fc, deg_s_fc,
                                                  cur_fc, pack_fc, EF);
    fill_pack_kernel<<<eblocks, 256, 0, stream>>>(cf_src, cf_dst, w_cf, deg_s_cf,
                                                  cur_cf, pack_cf, EF);

    // h1b = bf16(x_fact @ W1_fc)
    gemm_dsplit_kernel<<<(NF + 127) / 128, 256, 0, stream>>>(x_fact, b1h, b1l, h1b, NF, DF);

    // c1 = relu(aggregate + b1_fc)
    agg_fc_kernel<<<NC, 128, 0, stream>>>(off_fc, pack_fc, deg_d_fc, h1b, b1_fc, c1);

    // h2b = bf16(c1 @ W2_cf)
    gemm_dsplit_kernel<<<(NC + 127) / 128, 256, 0, stream>>>(c1, b2h, b2l, h2b, NC, H);

    // f2 aggregation fused with mean-pool accumulation
    agg_cf_pool_kernel<<<NF / FPB, 128, 0, stream>>>(off_cf, pack_cf, deg_d_cf, h2b, b2_cf,
                                                     batch, pooled, bcnt);

    final_kernel<<<1, 256, 0, stream>>>(pooled, bcnt, Wc, bc, out);
}